// Round 2
// baseline (95415.228 us; speedup 1.0000x reference)
//
#include <hip/hip_runtime.h>
#include <math.h>

constexpr int kB  = 128;
constexpr int kT  = 1024;
constexpr int kD  = 32;
constexpr int kH  = 64;
constexpr int kW  = 128;
constexpr int kC  = kD + 1;    // 33
constexpr int kO  = kH * kC;   // 2112
constexpr int kIN = kH + 1;    // 65
constexpr int BLOCK = 1024;    // 16 waves

// ---- int16 workspace layout (u32 units) ----
constexpr int WS_W2  = 0;            // 135168 u32 (2112 rows * 64 words), tiled
constexpr int WS_W1  = 135168;       // 8192 u32
constexpr int WS_W0  = 143360;       // 4224 u32
constexpr int WS_SC2 = 147584;       // 2112 f32 row scales
constexpr int WS_SC1 = 149696;       // 128
constexpr int WS_SC0 = 149824;       // 128
constexpr int WS_TOT = 149952;       // u32 -> 599,808 bytes

// parked W2 R-blocks: {0,1,2,3,32} -> LDS slots {0,1,2,3,4}
constexpr int PARKED = 5;

__device__ __forceinline__ float fast_sigmoid(float x) { return 1.0f / (1.0f + __expf(-x)); }
__device__ __forceinline__ float lipswish_f(float x)   { return 0.909f * x * fast_sigmoid(x); }
__device__ __forceinline__ float fast_tanh(float x) {
    float ax = fabsf(x);
    float e  = __expf(2.0f * ax);
    float r  = 1.0f - 2.0f / (e + 1.0f);
    return copysignf(r, x);
}
__device__ __forceinline__ float dot4(float4 a, float4 b) {
    return a.x * b.x + a.y * b.y + a.z * b.z + a.w * b.w;
}
__device__ __forceinline__ float fma2i(unsigned u, float z0, float z1, float acc) {
    int lo = (int)(short)(u & 0xffffu);
    int hi = ((int)u) >> 16;
    acc += (float)lo * z0 + (float)hi * z1;
    return acc;
}
__device__ __forceinline__ float fma8i(uint4 u, float4 zl, float4 zh, float acc) {
    acc = fma2i(u.x, zl.x, zl.y, acc);
    acc = fma2i(u.y, zl.z, zl.w, acc);
    acc = fma2i(u.z, zh.x, zh.y, acc);
    acc = fma2i(u.w, zh.z, zh.w, acc);
    return acc;
}
__device__ __forceinline__ int q15(float w, float inv) {
    float q = rintf(w * inv);
    q = fmaxf(-32767.0f, fminf(32767.0f, q));
    return (int)q;
}
__device__ __forceinline__ unsigned pack16(int a, int b) {
    return ((unsigned)a & 0xffffu) | ((unsigned)b << 16);
}

// one wave (64 threads) per row; rows: [0,2112) W2, [2112,2240) W1, [2240,2368) W0
__global__ __launch_bounds__(64)
void prep_kernel(const float* __restrict__ vW0, const float* __restrict__ vW1,
                 const float* __restrict__ vW2, unsigned* __restrict__ ws)
{
    const int row  = blockIdx.x;
    const int lane = threadIdx.x;
    float* scf = (float*)ws;

    if (row < kO) {                                   // vW2 row, 128 cols
        const float* src = vW2 + (size_t)row * kW;
        float m = fmaxf(fabsf(src[lane]), fabsf(src[lane + 64]));
        #pragma unroll
        for (int s = 1; s < 64; s <<= 1) m = fmaxf(m, __shfl_xor(m, s));
        float inv = (m > 0.0f) ? 32767.0f / m : 0.0f;
        if (lane == 0) scf[WS_SC2 + row] = (m > 0.0f) ? m / 32767.0f : 0.0f;
        int w = lane;
        unsigned pk = pack16(q15(src[2 * w], inv), q15(src[2 * w + 1], inv));
        int R = row >> 6, r = row & 63, q = w >> 2, e = w & 3;
        ws[WS_W2 + (((R * 16 + q) * 64 + r) << 2) + e] = pk;
    } else if (row < kO + kW) {                       // vW1 row, 128 cols
        int r = row - kO;
        const float* src = vW1 + (size_t)r * kW;
        float m = fmaxf(fabsf(src[lane]), fabsf(src[lane + 64]));
        #pragma unroll
        for (int s = 1; s < 64; s <<= 1) m = fmaxf(m, __shfl_xor(m, s));
        float inv = (m > 0.0f) ? 32767.0f / m : 0.0f;
        if (lane == 0) scf[WS_SC1 + r] = (m > 0.0f) ? m / 32767.0f : 0.0f;
        int w = lane;
        ws[WS_W1 + r * 64 + w] = pack16(q15(src[2 * w], inv), q15(src[2 * w + 1], inv));
    } else {                                          // vW0 row, 65 cols
        int r = row - kO - kW;
        const float* src = vW0 + (size_t)r * kIN;
        float m = fabsf(src[lane]);
        if (lane == 0) m = fmaxf(m, fabsf(src[64]));
        #pragma unroll
        for (int s = 1; s < 64; s <<= 1) m = fmaxf(m, __shfl_xor(m, s));
        float inv = (m > 0.0f) ? 32767.0f / m : 0.0f;
        if (lane == 0) scf[WS_SC0 + r] = (m > 0.0f) ? m / 32767.0f : 0.0f;
        if (lane < 33) {
            int c0 = 2 * lane, c1 = 2 * lane + 1;
            int qa = q15(src[c0], inv);
            int qb = (c1 < kIN) ? q15(src[c1], inv) : 0;
            ws[WS_W0 + r * 33 + lane] = pack16(qa, qb);
        }
    }
}

template <int QI>
__global__ __launch_bounds__(BLOCK)
void cde_kernel(
    const float* __restrict__ ts,  const float* __restrict__ ys,
    const float* __restrict__ iW0, const float* __restrict__ ib0,
    const float* __restrict__ iW1, const float* __restrict__ ib1,
    const float* __restrict__ iW2, const float* __restrict__ ib2,
    const float* __restrict__ vW0, const float* __restrict__ vb0,
    const float* __restrict__ vW1, const float* __restrict__ vb1,
    const float* __restrict__ vW2, const float* __restrict__ vb2,
    const float* __restrict__ rW,  const float* __restrict__ rb,
    const unsigned* __restrict__ wsb,
    float* __restrict__ out)
{
    const int b  = blockIdx.x;
    const int t  = threadIdx.x;
    const int r8 = t >> 3;     // 0..127
    const int g  = t & 7;      // 0..7
    const int wv = t >> 6;     // wave 0..15
    const int ln = t & 63;     // lane

    // parked weights (int16) + state
    __shared__ __align__(16) uint4    s_w2[PARKED * 1024];  // 81920 B
    __shared__ __align__(16) unsigned s_w1[kW * 64];        // 32768 B
    __shared__ __align__(16) unsigned s_w0[kW * 33];        // 16896 B
    __shared__ __align__(16) float s_v[kO];                 // 8448 B
    __shared__ __align__(16) float s_z1[kW], s_z2[kW];
    __shared__ __align__(16) float s_inp[kIN + 1];          // [65] = 0 pad
    __shared__ float s_y[kH], s_yhat[kH], s_e[kH];
    __shared__ float s_x[3][34];                            // x_{i-1}, x_i, x_{i+1}

    const float*    ysb   = ys + (size_t)b * kT * kD;
    const uint4*    wsW2q = (const uint4*)(wsb + WS_W2);
    const float*    scf   = (const float*)wsb;

    const float bA  = vb2[t];
    const float bB  = vb2[t + 1024];
    const float bTl = (t < 512) ? vb2[2048 + r8] : 0.0f;
    const float b0r = vb0[r8];
    const float b1r = vb1[r8];
    const float sA  = QI ? scf[WS_SC2 + t] : 0.0f;
    const float sB  = QI ? scf[WS_SC2 + t + 1024] : 0.0f;
    const float sTl = (QI && t < 512) ? scf[WS_SC2 + 2048 + r8] : 0.0f;
    const float s0r = QI ? scf[WS_SC0 + r8] : 0.0f;
    const float s1r = QI ? scf[WS_SC1 + r8] : 0.0f;

    // ---- park weights in LDS (one-time) ----
    if (QI) {
        for (int idx = t; idx < PARKED * 1024; idx += BLOCK) {
            int slot = idx >> 10;
            int Rg = (slot < 4) ? slot : 32;
            s_w2[idx] = wsW2q[(size_t)Rg * 1024 + (idx & 1023)];
        }
        for (int idx = t; idx < kW * 64; idx += BLOCK) s_w1[idx] = wsb[WS_W1 + idx];
        for (int idx = t; idx < kW * 33; idx += BLOCK) s_w0[idx] = wsb[WS_W0 + idx];
    }

    // ---- x staging init: s_x[0]=x_0, s_x[1]=x_1, s_x[2]=0 ----
    float x_next = 0.0f;
    const float* yptr = nullptr;
    if (t < kC) {
        float x0v, x1v;
        if (t == 0) { x0v = ts[0]; x1v = ts[1]; }
        else {
            const float* p = ysb + (t - 1);
            x0v = p[0]; x1v = p[kD]; yptr = p + 2 * kD;
        }
        s_x[0][t] = x0v; s_x[1][t] = x1v; s_x[2][t] = 0.0f;
        x_next = x1v;
    }
    if (t == 0) s_inp[kIN] = 0.0f;          // pad
    __syncthreads();

    // ---- initial MLP (one-time, fp32) ----
    if (t < kW) {
        const float* wrow = iW0 + t * kC;
        float acc = ib0[t];
        #pragma unroll
        for (int c = 0; c < kC; c++) acc += wrow[c] * s_x[0][c];
        s_z1[t] = fmaxf(acc, 0.0f);
    }
    __syncthreads();
    if (t < kW) {
        const float4* wr = (const float4*)(iW1 + t * kW);
        const float4* z4 = (const float4*)s_z1;
        float acc = ib1[t];
        #pragma unroll 8
        for (int q = 0; q < kW / 4; q++) acc += dot4(wr[q], z4[q]);
        s_z2[t] = fmaxf(acc, 0.0f);
    }
    __syncthreads();
    if (t < kH) {
        const float4* wr = (const float4*)(iW2 + t * kW);
        const float4* z4 = (const float4*)s_z2;
        float acc = ib2[t];
        #pragma unroll 8
        for (int q = 0; q < kW / 4; q++) acc += dot4(wr[q], z4[q]);
        s_y[t] = acc; s_yhat[t] = acc;
        s_inp[1 + t] = acc;
    }
    if (t == 0) s_inp[0] = ts[0];
    __syncthreads();

    // ---- S3 pointers ----
    const uint4* gA = wsW2q + (size_t)(wv * 16) * 64 + ln;          // rows wv*64..
    const uint4* gB = wsW2q + (size_t)((wv + 16) * 16) * 64 + ln;   // rows 1024+wv*64..
    const uint4* lA = s_w2 + wv * 1024 + ln;                        // valid if wv<4
    const bool aL = (wv < 4);

    // ---- main scan: 4 barriers per step ----
    for (int i = 0; i < kT; i++) {
        const int i0  = i % 3;
        const int ip1 = (i + 1) % 3;
        const int im1 = (i + 2) % 3;

        // prologue prefetch for S3: issue early, complete under S1+S2
        uint4 b0a, b0b, b1a, b1b, a0a, a0b, a1a, a1b;
        if (QI) {
            b0a = gB[0];   b0b = gB[64];
            b1a = gB[128]; b1b = gB[192];
            if (!aL) { a0a = gA[0]; a0b = gA[64]; a1a = gA[128]; a1b = gA[192]; }
        }

        // ===== S1: layer1 (65->128), split-k-8 ; x_{i+1} publish + x_{i+2} prefetch =====
        {
            float acc = 0.0f;
            if (QI) {
                const unsigned* rowp = s_w0 + r8 * 33;
                #pragma unroll
                for (int m = 0; m < 5; m++) {
                    int p = g + 8 * m;
                    if (p < 33) acc = fma2i(rowp[p], s_inp[2 * p], s_inp[2 * p + 1], acc);
                }
            } else {
                const float* rowp = vW0 + r8 * kIN;
                #pragma unroll
                for (int m = 0; m < 5; m++) {
                    int p = g + 8 * m;
                    if (p < 33) {
                        float w0 = rowp[2 * p];
                        float w1 = (2 * p + 1 < kIN) ? rowp[2 * p + 1] : 0.0f;
                        acc += w0 * s_inp[2 * p] + w1 * s_inp[2 * p + 1];
                    }
                }
            }
            acc += __shfl_xor(acc, 1);
            acc += __shfl_xor(acc, 2);
            acc += __shfl_xor(acc, 4);
            if (g == 0) s_z1[r8] = lipswish_f(b0r + (QI ? s0r * acc : acc));
        }
        if (t < kC && i + 1 < kT) {
            s_x[ip1][t] = x_next;
            if (i + 2 < kT) {
                if (t == 0) x_next = ts[i + 2];
                else { x_next = *yptr; yptr += kD; }
            }
        }
        __syncthreads();

        // ===== S2: layer2 (128->128), split-k-8 =====
        {
            float acc = 0.0f;
            #pragma unroll
            for (int m = 0; m < 2; m++) {
                int ch = g + 8 * m;
                int c0 = 8 * ch;
                const float4* z4 = (const float4*)(s_z1 + c0);
                float4 za = z4[0], zb = z4[1];
                if (QI) {
                    uint4 u = *(const uint4*)(s_w1 + r8 * 64 + 4 * ch);
                    acc = fma8i(u, za, zb, acc);
                } else {
                    const float* wr = vW1 + r8 * kW + c0;
                    acc += dot4(*(const float4*)wr, za) + dot4(*(const float4*)(wr + 4), zb);
                }
            }
            acc += __shfl_xor(acc, 1);
            acc += __shfl_xor(acc, 2);
            acc += __shfl_xor(acc, 4);
            if (g == 0) s_z2[r8] = lipswish_f(b1r + (QI ? s1r * acc : acc));
        }
        __syncthreads();

        // ===== S3 main: rows t and t+1024 ; depth-2 global prefetch =====
        if (QI) {
            float acc0 = 0.0f, acc1 = 0.0f;
            #pragma unroll
            for (int m = 0; m < 8; m++) {
                uint4 nba, nbb, naa, nab;
                if (m < 6) {
                    nba = gB[(2 * m + 4) * 64]; nbb = gB[(2 * m + 5) * 64];
                    if (!aL) { naa = gA[(2 * m + 4) * 64]; nab = gA[(2 * m + 5) * 64]; }
                }
                uint4 wa0, wa1;
                if (aL) { wa0 = lA[(2 * m) * 64]; wa1 = lA[(2 * m + 1) * 64]; }
                else    { wa0 = a0a; wa1 = a0b; }
                const float4* z4 = (const float4*)(s_z2 + 16 * m);
                float4 z0 = z4[0], z1 = z4[1], z2 = z4[2], z3 = z4[3];
                acc0 = fma8i(wa0, z0, z1, acc0);
                acc0 = fma8i(wa1, z2, z3, acc0);
                acc1 = fma8i(b0a, z0, z1, acc1);
                acc1 = fma8i(b0b, z2, z3, acc1);
                b0a = b1a; b0b = b1b; b1a = nba; b1b = nbb;
                if (!aL) { a0a = a1a; a0b = a1b; a1a = naa; a1b = nab; }
            }
            s_v[t]        = fast_tanh(bA + sA * acc0);
            s_v[t + 1024] = fast_tanh(bB + sB * acc1);
        } else {
            float acc0 = 0.0f, acc1 = 0.0f;
            #pragma unroll 2
            for (int m = 0; m < 8; m++) {
                const float4* z4 = (const float4*)(s_z2 + 16 * m);
                float4 z0 = z4[0], z1 = z4[1], z2 = z4[2], z3 = z4[3];
                const float4* rA = (const float4*)(vW2 + (size_t)t * kW + 16 * m);
                const float4* rB = (const float4*)(vW2 + (size_t)(t + 1024) * kW + 16 * m);
                acc0 += dot4(rA[0], z0) + dot4(rA[1], z1) + dot4(rA[2], z2) + dot4(rA[3], z3);
                acc1 += dot4(rB[0], z0) + dot4(rB[1], z1) + dot4(rB[2], z2) + dot4(rB[3], z3);
            }
            s_v[t]        = fast_tanh(bA + acc0);
            s_v[t + 1024] = fast_tanh(bB + acc1);
        }
        // ===== S3 tail: rows 2048..2111, split-k-8 (LDS slot 4) =====
        if (t < 512) {
            int c0 = 16 * g;
            const float4* z4 = (const float4*)(s_z2 + c0);
            float4 z0 = z4[0], z1 = z4[1], z2 = z4[2], z3 = z4[3];
            float acc = 0.0f;
            if (QI) {
                uint4 u0 = s_w2[4 * 1024 + (2 * g) * 64 + r8];
                uint4 u1 = s_w2[4 * 1024 + (2 * g + 1) * 64 + r8];
                acc = fma8i(u0, z0, z1, acc);
                acc = fma8i(u1, z2, z3, acc);
            } else {
                const float4* wr = (const float4*)(vW2 + (size_t)(2048 + r8) * kW + c0);
                acc += dot4(wr[0], z0) + dot4(wr[1], z1) + dot4(wr[2], z2) + dot4(wr[3], z3);
            }
            acc += __shfl_xor(acc, 1);
            acc += __shfl_xor(acc, 2);
            acc += __shfl_xor(acc, 4);
            if (g == 0) s_v[2048 + r8] = fast_tanh(bTl + (QI ? sTl * acc : acc));
        }
        __syncthreads();

        // ===== S4 fused: y update (dx_{i-1}) + e/yhat (dx_i) =====
        if (t < kH) {
            const float* vr = s_v + t * kC;
            const float* xm = s_x[im1];
            const float* xc = s_x[i0];
            const float* xp = s_x[ip1];
            float dA = 0.0f, dB = 0.0f;
            #pragma unroll
            for (int c = 0; c < kC; c++) {
                float vv = vr[c];
                dA += vv * (xc[c] - xm[c]);
                dB += vv * (xp[c] - xc[c]);
            }
            if (i > 0) s_y[t] += 0.5f * (s_e[t] + dA);
            if (i < kT - 1) {
                s_e[t] = dB;
                float yh = 2.0f * s_y[t] - s_yhat[t] + dB;
                s_yhat[t] = yh;
                s_inp[1 + t] = yh;
            }
        }
        if (t == 0 && i < kT - 1) s_inp[0] = s_x[ip1][0];
        __syncthreads();
    }

    // ---- readout ----
    if (t == 0) {
        float acc = rb[0];
        #pragma unroll
        for (int h = 0; h < kH; h++) acc += s_y[h] * rW[h];
        out[b] = acc;
    }
}

extern "C" void kernel_launch(void* const* d_in, const int* in_sizes, int n_in,
                              void* d_out, int out_size, void* d_ws, size_t ws_size,
                              hipStream_t stream)
{
    const float* ts  = (const float*)d_in[0];
    const float* ys  = (const float*)d_in[1];
    const float* iW0 = (const float*)d_in[2];
    const float* ib0 = (const float*)d_in[3];
    const float* iW1 = (const float*)d_in[4];
    const float* ib1 = (const float*)d_in[5];
    const float* iW2 = (const float*)d_in[6];
    const float* ib2 = (const float*)d_in[7];
    const float* vW0 = (const float*)d_in[8];
    const float* vb0 = (const float*)d_in[9];
    const float* vW1 = (const float*)d_in[10];
    const float* vb1 = (const float*)d_in[11];
    const float* vW2 = (const float*)d_in[12];
    const float* vb2 = (const float*)d_in[13];
    const float* rW  = (const float*)d_in[14];
    const float* rb  = (const float*)d_in[15];
    float* out = (float*)d_out;
    unsigned* ws = (unsigned*)d_ws;

    if (ws_size >= (size_t)WS_TOT * 4) {
        hipLaunchKernelGGL(prep_kernel, dim3(kO + kW + kW), dim3(64), 0, stream,
                           vW0, vW1, vW2, ws);
        hipLaunchKernelGGL((cde_kernel<1>), dim3(kB), dim3(BLOCK), 0, stream,
                           ts, ys, iW0, ib0, iW1, ib1, iW2, ib2,
                           vW0, vb0, vW1, vb1, vW2, vb2, rW, rb, ws, out);
    } else {
        hipLaunchKernelGGL((cde_kernel<0>), dim3(kB), dim3(BLOCK), 0, stream,
                           ts, ys, iW0, ib0, iW1, ib1, iW2, ib2,
                           vW0, vb0, vW1, vb1, vW2, vb2, rW, rb, ws, out);
    }
}

// Round 3
// 94261.139 us; speedup vs baseline: 1.0122x; 1.0122x over previous
//
#include <hip/hip_runtime.h>
#include <math.h>

constexpr int kB  = 128;
constexpr int kT  = 1024;
constexpr int kD  = 32;
constexpr int kH  = 64;
constexpr int kW  = 128;
constexpr int kC  = kD + 1;    // 33
constexpr int kO  = kH * kC;   // 2112
constexpr int kIN = kH + 1;    // 65
constexpr int BLOCK = 1024;    // 16 waves

// ---- int16 workspace layout (u32 units) ----
constexpr int WS_W2  = 0;            // 135168 u32 (2112 rows * 64 words), tiled
constexpr int WS_W1  = 135168;       // 8192 u32
constexpr int WS_W0  = 143360;       // 4224 u32
constexpr int WS_SC2 = 147584;       // 2112 f32 row scales
constexpr int WS_SC1 = 149696;       // 128
constexpr int WS_SC0 = 149824;       // 128
constexpr int WS_TOT = 149952;       // u32 -> 599,808 bytes

// parked W2 R-blocks: {0,1,2,3,32} -> LDS slots {0,1,2,3,4}
constexpr int PARKED = 5;

__device__ __forceinline__ float fast_sigmoid(float x) { return 1.0f / (1.0f + __expf(-x)); }
__device__ __forceinline__ float lipswish_f(float x)   { return 0.909f * x * fast_sigmoid(x); }
__device__ __forceinline__ float fast_tanh(float x) {
    float ax = fabsf(x);
    float e  = __expf(2.0f * ax);
    float r  = 1.0f - 2.0f / (e + 1.0f);
    return copysignf(r, x);
}
__device__ __forceinline__ float dot4(float4 a, float4 b) {
    return a.x * b.x + a.y * b.y + a.z * b.z + a.w * b.w;
}
__device__ __forceinline__ float fma2i(unsigned u, float z0, float z1, float acc) {
    int lo = (int)(short)(u & 0xffffu);
    int hi = ((int)u) >> 16;
    acc += (float)lo * z0 + (float)hi * z1;
    return acc;
}
__device__ __forceinline__ float fma8i(uint4 u, float4 zl, float4 zh, float acc) {
    acc = fma2i(u.x, zl.x, zl.y, acc);
    acc = fma2i(u.y, zl.z, zl.w, acc);
    acc = fma2i(u.z, zh.x, zh.y, acc);
    acc = fma2i(u.w, zh.z, zh.w, acc);
    return acc;
}
__device__ __forceinline__ int q15(float w, float inv) {
    float q = rintf(w * inv);
    q = fmaxf(-32767.0f, fminf(32767.0f, q));
    return (int)q;
}
__device__ __forceinline__ unsigned pack16(int a, int b) {
    return ((unsigned)a & 0xffffu) | ((unsigned)b << 16);
}

// one wave (64 threads) per row; rows: [0,2112) W2, [2112,2240) W1, [2240,2368) W0
__global__ __launch_bounds__(64)
void prep_kernel(const float* __restrict__ vW0, const float* __restrict__ vW1,
                 const float* __restrict__ vW2, unsigned* __restrict__ ws)
{
    const int row  = blockIdx.x;
    const int lane = threadIdx.x;
    float* scf = (float*)ws;

    if (row < kO) {                                   // vW2 row, 128 cols
        const float* src = vW2 + (size_t)row * kW;
        float m = fmaxf(fabsf(src[lane]), fabsf(src[lane + 64]));
        #pragma unroll
        for (int s = 1; s < 64; s <<= 1) m = fmaxf(m, __shfl_xor(m, s));
        float inv = (m > 0.0f) ? 32767.0f / m : 0.0f;
        if (lane == 0) scf[WS_SC2 + row] = (m > 0.0f) ? m / 32767.0f : 0.0f;
        int w = lane;
        unsigned pk = pack16(q15(src[2 * w], inv), q15(src[2 * w + 1], inv));
        int R = row >> 6, r = row & 63, q = w >> 2, e = w & 3;
        ws[WS_W2 + (((R * 16 + q) * 64 + r) << 2) + e] = pk;
    } else if (row < kO + kW) {                       // vW1 row, 128 cols
        int r = row - kO;
        const float* src = vW1 + (size_t)r * kW;
        float m = fmaxf(fabsf(src[lane]), fabsf(src[lane + 64]));
        #pragma unroll
        for (int s = 1; s < 64; s <<= 1) m = fmaxf(m, __shfl_xor(m, s));
        float inv = (m > 0.0f) ? 32767.0f / m : 0.0f;
        if (lane == 0) scf[WS_SC1 + r] = (m > 0.0f) ? m / 32767.0f : 0.0f;
        int w = lane;
        ws[WS_W1 + r * 64 + w] = pack16(q15(src[2 * w], inv), q15(src[2 * w + 1], inv));
    } else {                                          // vW0 row, 65 cols
        int r = row - kO - kW;
        const float* src = vW0 + (size_t)r * kIN;
        float m = fabsf(src[lane]);
        if (lane == 0) m = fmaxf(m, fabsf(src[64]));
        #pragma unroll
        for (int s = 1; s < 64; s <<= 1) m = fmaxf(m, __shfl_xor(m, s));
        float inv = (m > 0.0f) ? 32767.0f / m : 0.0f;
        if (lane == 0) scf[WS_SC0 + r] = (m > 0.0f) ? m / 32767.0f : 0.0f;
        if (lane < 33) {
            int c0 = 2 * lane, c1 = 2 * lane + 1;
            int qa = q15(src[c0], inv);
            int qb = (c1 < kIN) ? q15(src[c1], inv) : 0;
            ws[WS_W0 + r * 33 + lane] = pack16(qa, qb);
        }
    }
}

// __launch_bounds__(1024, 4): 16 waves = 4 waves/EU -> VGPR cap 128 (not 64).
// Round-2's implicit cap of 64 VGPRs spilled ~1.2 KB/thread/step to scratch
// (78 GB WRITE_SIZE). The S3 depth-2 prefetch needs ~105 live VGPRs.
template <int QI>
__global__ __launch_bounds__(BLOCK, 4)
void cde_kernel(
    const float* __restrict__ ts,  const float* __restrict__ ys,
    const float* __restrict__ iW0, const float* __restrict__ ib0,
    const float* __restrict__ iW1, const float* __restrict__ ib1,
    const float* __restrict__ iW2, const float* __restrict__ ib2,
    const float* __restrict__ vW0, const float* __restrict__ vb0,
    const float* __restrict__ vW1, const float* __restrict__ vb1,
    const float* __restrict__ vW2, const float* __restrict__ vb2,
    const float* __restrict__ rW,  const float* __restrict__ rb,
    const unsigned* __restrict__ wsb,
    float* __restrict__ out)
{
    const int b  = blockIdx.x;
    const int t  = threadIdx.x;
    const int r8 = t >> 3;     // 0..127
    const int g  = t & 7;      // 0..7
    const int wv = t >> 6;     // wave 0..15
    const int ln = t & 63;     // lane

    // parked weights (int16) + state
    __shared__ __align__(16) uint4    s_w2[PARKED * 1024];  // 81920 B
    __shared__ __align__(16) unsigned s_w1[kW * 64];        // 32768 B
    __shared__ __align__(16) unsigned s_w0[kW * 33];        // 16896 B
    __shared__ __align__(16) float s_v[kO];                 // 8448 B
    __shared__ __align__(16) float s_z1[kW], s_z2[kW];
    __shared__ __align__(16) float s_inp[kIN + 1];          // [65] = 0 pad
    __shared__ float s_y[kH], s_yhat[kH], s_e[kH];
    __shared__ float s_x[3][34];                            // x_{i-1}, x_i, x_{i+1}

    const float*    ysb   = ys + (size_t)b * kT * kD;
    const uint4*    wsW2q = (const uint4*)(wsb + WS_W2);
    const float*    scf   = (const float*)wsb;

    const float bA  = vb2[t];
    const float bB  = vb2[t + 1024];
    const float bTl = (t < 512) ? vb2[2048 + r8] : 0.0f;
    const float b0r = vb0[r8];
    const float b1r = vb1[r8];
    const float sA  = QI ? scf[WS_SC2 + t] : 0.0f;
    const float sB  = QI ? scf[WS_SC2 + t + 1024] : 0.0f;
    const float sTl = (QI && t < 512) ? scf[WS_SC2 + 2048 + r8] : 0.0f;
    const float s0r = QI ? scf[WS_SC0 + r8] : 0.0f;
    const float s1r = QI ? scf[WS_SC1 + r8] : 0.0f;

    // ---- park weights in LDS (one-time) ----
    if (QI) {
        for (int idx = t; idx < PARKED * 1024; idx += BLOCK) {
            int slot = idx >> 10;
            int Rg = (slot < 4) ? slot : 32;
            s_w2[idx] = wsW2q[(size_t)Rg * 1024 + (idx & 1023)];
        }
        for (int idx = t; idx < kW * 64; idx += BLOCK) s_w1[idx] = wsb[WS_W1 + idx];
        for (int idx = t; idx < kW * 33; idx += BLOCK) s_w0[idx] = wsb[WS_W0 + idx];
    }

    // ---- x staging init: s_x[0]=x_0, s_x[1]=x_1, s_x[2]=0 ----
    float x_next = 0.0f;
    const float* yptr = nullptr;
    if (t < kC) {
        float x0v, x1v;
        if (t == 0) { x0v = ts[0]; x1v = ts[1]; }
        else {
            const float* p = ysb + (t - 1);
            x0v = p[0]; x1v = p[kD]; yptr = p + 2 * kD;
        }
        s_x[0][t] = x0v; s_x[1][t] = x1v; s_x[2][t] = 0.0f;
        x_next = x1v;
    }
    if (t == 0) s_inp[kIN] = 0.0f;          // pad
    __syncthreads();

    // ---- initial MLP (one-time, fp32) ----
    if (t < kW) {
        const float* wrow = iW0 + t * kC;
        float acc = ib0[t];
        #pragma unroll
        for (int c = 0; c < kC; c++) acc += wrow[c] * s_x[0][c];
        s_z1[t] = fmaxf(acc, 0.0f);
    }
    __syncthreads();
    if (t < kW) {
        const float4* wr = (const float4*)(iW1 + t * kW);
        const float4* z4 = (const float4*)s_z1;
        float acc = ib1[t];
        #pragma unroll 8
        for (int q = 0; q < kW / 4; q++) acc += dot4(wr[q], z4[q]);
        s_z2[t] = fmaxf(acc, 0.0f);
    }
    __syncthreads();
    if (t < kH) {
        const float4* wr = (const float4*)(iW2 + t * kW);
        const float4* z4 = (const float4*)s_z2;
        float acc = ib2[t];
        #pragma unroll 8
        for (int q = 0; q < kW / 4; q++) acc += dot4(wr[q], z4[q]);
        s_y[t] = acc; s_yhat[t] = acc;
        s_inp[1 + t] = acc;
    }
    if (t == 0) s_inp[0] = ts[0];
    __syncthreads();

    // ---- S3 pointers ----
    const uint4* gA = wsW2q + (size_t)(wv * 16) * 64 + ln;          // rows wv*64..
    const uint4* gB = wsW2q + (size_t)((wv + 16) * 16) * 64 + ln;   // rows 1024+wv*64..
    const uint4* lA = s_w2 + wv * 1024 + ln;                        // valid if wv<4
    const bool aL = (wv < 4);

    // ---- main scan: 4 barriers per step ----
    for (int i = 0; i < kT; i++) {
        const int i0  = i % 3;
        const int ip1 = (i + 1) % 3;
        const int im1 = (i + 2) % 3;

        // prologue prefetch for S3: issue early, complete under S1+S2
        uint4 b0a, b0b, b1a, b1b, a0a, a0b, a1a, a1b;
        if (QI) {
            b0a = gB[0];   b0b = gB[64];
            b1a = gB[128]; b1b = gB[192];
            if (!aL) { a0a = gA[0]; a0b = gA[64]; a1a = gA[128]; a1b = gA[192]; }
        }

        // ===== S1: layer1 (65->128), split-k-8 ; x_{i+1} publish + x_{i+2} prefetch =====
        {
            float acc = 0.0f;
            if (QI) {
                const unsigned* rowp = s_w0 + r8 * 33;
                #pragma unroll
                for (int m = 0; m < 5; m++) {
                    int p = g + 8 * m;
                    if (p < 33) acc = fma2i(rowp[p], s_inp[2 * p], s_inp[2 * p + 1], acc);
                }
            } else {
                const float* rowp = vW0 + r8 * kIN;
                #pragma unroll
                for (int m = 0; m < 5; m++) {
                    int p = g + 8 * m;
                    if (p < 33) {
                        float w0 = rowp[2 * p];
                        float w1 = (2 * p + 1 < kIN) ? rowp[2 * p + 1] : 0.0f;
                        acc += w0 * s_inp[2 * p] + w1 * s_inp[2 * p + 1];
                    }
                }
            }
            acc += __shfl_xor(acc, 1);
            acc += __shfl_xor(acc, 2);
            acc += __shfl_xor(acc, 4);
            if (g == 0) s_z1[r8] = lipswish_f(b0r + (QI ? s0r * acc : acc));
        }
        if (t < kC && i + 1 < kT) {
            s_x[ip1][t] = x_next;
            if (i + 2 < kT) {
                if (t == 0) x_next = ts[i + 2];
                else { x_next = *yptr; yptr += kD; }
            }
        }
        __syncthreads();

        // ===== S2: layer2 (128->128), split-k-8 =====
        {
            float acc = 0.0f;
            #pragma unroll
            for (int m = 0; m < 2; m++) {
                int ch = g + 8 * m;
                int c0 = 8 * ch;
                const float4* z4 = (const float4*)(s_z1 + c0);
                float4 za = z4[0], zb = z4[1];
                if (QI) {
                    uint4 u = *(const uint4*)(s_w1 + r8 * 64 + 4 * ch);
                    acc = fma8i(u, za, zb, acc);
                } else {
                    const float* wr = vW1 + r8 * kW + c0;
                    acc += dot4(*(const float4*)wr, za) + dot4(*(const float4*)(wr + 4), zb);
                }
            }
            acc += __shfl_xor(acc, 1);
            acc += __shfl_xor(acc, 2);
            acc += __shfl_xor(acc, 4);
            if (g == 0) s_z2[r8] = lipswish_f(b1r + (QI ? s1r * acc : acc));
        }
        __syncthreads();

        // ===== S3 main: rows t and t+1024 ; depth-2 global prefetch =====
        if (QI) {
            float acc0 = 0.0f, acc1 = 0.0f;
            #pragma unroll
            for (int m = 0; m < 8; m++) {
                uint4 nba, nbb, naa, nab;
                if (m < 6) {
                    nba = gB[(2 * m + 4) * 64]; nbb = gB[(2 * m + 5) * 64];
                    if (!aL) { naa = gA[(2 * m + 4) * 64]; nab = gA[(2 * m + 5) * 64]; }
                }
                uint4 wa0, wa1;
                if (aL) { wa0 = lA[(2 * m) * 64]; wa1 = lA[(2 * m + 1) * 64]; }
                else    { wa0 = a0a; wa1 = a0b; }
                const float4* z4 = (const float4*)(s_z2 + 16 * m);
                float4 z0 = z4[0], z1 = z4[1], z2 = z4[2], z3 = z4[3];
                acc0 = fma8i(wa0, z0, z1, acc0);
                acc0 = fma8i(wa1, z2, z3, acc0);
                acc1 = fma8i(b0a, z0, z1, acc1);
                acc1 = fma8i(b0b, z2, z3, acc1);
                b0a = b1a; b0b = b1b; b1a = nba; b1b = nbb;
                if (!aL) { a0a = a1a; a0b = a1b; a1a = naa; a1b = nab; }
            }
            s_v[t]        = fast_tanh(bA + sA * acc0);
            s_v[t + 1024] = fast_tanh(bB + sB * acc1);
        } else {
            float acc0 = 0.0f, acc1 = 0.0f;
            #pragma unroll 2
            for (int m = 0; m < 8; m++) {
                const float4* z4 = (const float4*)(s_z2 + 16 * m);
                float4 z0 = z4[0], z1 = z4[1], z2 = z4[2], z3 = z4[3];
                const float4* rA = (const float4*)(vW2 + (size_t)t * kW + 16 * m);
                const float4* rB = (const float4*)(vW2 + (size_t)(t + 1024) * kW + 16 * m);
                acc0 += dot4(rA[0], z0) + dot4(rA[1], z1) + dot4(rA[2], z2) + dot4(rA[3], z3);
                acc1 += dot4(rB[0], z0) + dot4(rB[1], z1) + dot4(rB[2], z2) + dot4(rB[3], z3);
            }
            s_v[t]        = fast_tanh(bA + acc0);
            s_v[t + 1024] = fast_tanh(bB + acc1);
        }
        // ===== S3 tail: rows 2048..2111, split-k-8 (LDS slot 4) =====
        if (t < 512) {
            int c0 = 16 * g;
            const float4* z4 = (const float4*)(s_z2 + c0);
            float4 z0 = z4[0], z1 = z4[1], z2 = z4[2], z3 = z4[3];
            float acc = 0.0f;
            if (QI) {
                uint4 u0 = s_w2[4 * 1024 + (2 * g) * 64 + r8];
                uint4 u1 = s_w2[4 * 1024 + (2 * g + 1) * 64 + r8];
                acc = fma8i(u0, z0, z1, acc);
                acc = fma8i(u1, z2, z3, acc);
            } else {
                const float4* wr = (const float4*)(vW2 + (size_t)(2048 + r8) * kW + c0);
                acc += dot4(wr[0], z0) + dot4(wr[1], z1) + dot4(wr[2], z2) + dot4(wr[3], z3);
            }
            acc += __shfl_xor(acc, 1);
            acc += __shfl_xor(acc, 2);
            acc += __shfl_xor(acc, 4);
            if (g == 0) s_v[2048 + r8] = fast_tanh(bTl + (QI ? sTl * acc : acc));
        }
        __syncthreads();

        // ===== S4 fused: y update (dx_{i-1}) + e/yhat (dx_i) =====
        if (t < kH) {
            const float* vr = s_v + t * kC;
            const float* xm = s_x[im1];
            const float* xc = s_x[i0];
            const float* xp = s_x[ip1];
            float dA = 0.0f, dB = 0.0f;
            #pragma unroll
            for (int c = 0; c < kC; c++) {
                float vv = vr[c];
                dA += vv * (xc[c] - xm[c]);
                dB += vv * (xp[c] - xc[c]);
            }
            if (i > 0) s_y[t] += 0.5f * (s_e[t] + dA);
            if (i < kT - 1) {
                s_e[t] = dB;
                float yh = 2.0f * s_y[t] - s_yhat[t] + dB;
                s_yhat[t] = yh;
                s_inp[1 + t] = yh;
            }
        }
        if (t == 0 && i < kT - 1) s_inp[0] = s_x[ip1][0];
        __syncthreads();
    }

    // ---- readout ----
    if (t == 0) {
        float acc = rb[0];
        #pragma unroll
        for (int h = 0; h < kH; h++) acc += s_y[h] * rW[h];
        out[b] = acc;
    }
}

extern "C" void kernel_launch(void* const* d_in, const int* in_sizes, int n_in,
                              void* d_out, int out_size, void* d_ws, size_t ws_size,
                              hipStream_t stream)
{
    const float* ts  = (const float*)d_in[0];
    const float* ys  = (const float*)d_in[1];
    const float* iW0 = (const float*)d_in[2];
    const float* ib0 = (const float*)d_in[3];
    const float* iW1 = (const float*)d_in[4];
    const float* ib1 = (const float*)d_in[5];
    const float* iW2 = (const float*)d_in[6];
    const float* ib2 = (const float*)d_in[7];
    const float* vW0 = (const float*)d_in[8];
    const float* vb0 = (const float*)d_in[9];
    const float* vW1 = (const float*)d_in[10];
    const float* vb1 = (const float*)d_in[11];
    const float* vW2 = (const float*)d_in[12];
    const float* vb2 = (const float*)d_in[13];
    const float* rW  = (const float*)d_in[14];
    const float* rb  = (const float*)d_in[15];
    float* out = (float*)d_out;
    unsigned* ws = (unsigned*)d_ws;

    if (ws_size >= (size_t)WS_TOT * 4) {
        hipLaunchKernelGGL(prep_kernel, dim3(kO + kW + kW), dim3(64), 0, stream,
                           vW0, vW1, vW2, ws);
        hipLaunchKernelGGL((cde_kernel<1>), dim3(kB), dim3(BLOCK), 0, stream,
                           ts, ys, iW0, ib0, iW1, ib1, iW2, ib2,
                           vW0, vb0, vW1, vb1, vW2, vb2, rW, rb, ws, out);
    } else {
        hipLaunchKernelGGL((cde_kernel<0>), dim3(kB), dim3(BLOCK), 0, stream,
                           ts, ys, iW0, ib0, iW1, ib1, iW2, ib2,
                           vW0, vb0, vW1, vb1, vW2, vb2, rW, rb, ws, out);
    }
}

// Round 4
// 8409.087 us; speedup vs baseline: 11.3467x; 11.2094x over previous
//
#include <hip/hip_runtime.h>
#include <math.h>

constexpr int kB  = 128;
constexpr int kT  = 1024;
constexpr int kD  = 32;
constexpr int kH  = 64;
constexpr int kW  = 128;
constexpr int kC  = kD + 1;    // 33
constexpr int kO  = kH * kC;   // 2112
constexpr int kIN = kH + 1;    // 65
constexpr int BLOCK = 1024;    // 16 waves

// ---- int16 workspace layout (u32 units) ----
constexpr int WS_W2  = 0;            // 135168 u32 (2112 rows * 64 words), tiled
constexpr int WS_W1  = 135168;       // 8192 u32
constexpr int WS_W0  = 143360;       // 4224 u32
constexpr int WS_SC2 = 147584;       // 2112 f32 row scales
constexpr int WS_SC1 = 149696;       // 128
constexpr int WS_SC0 = 149824;       // 128
constexpr int WS_TOT = 149952;       // u32 -> 599,808 bytes

__device__ __forceinline__ float fast_sigmoid(float x) { return 1.0f / (1.0f + __expf(-x)); }
__device__ __forceinline__ float lipswish_f(float x)   { return 0.909f * x * fast_sigmoid(x); }
__device__ __forceinline__ float fast_tanh(float x) {
    float ax = fabsf(x);
    float e  = __expf(2.0f * ax);
    float r  = 1.0f - 2.0f / (e + 1.0f);
    return copysignf(r, x);
}
__device__ __forceinline__ float dot4(float4 a, float4 b) {
    return a.x * b.x + a.y * b.y + a.z * b.z + a.w * b.w;
}
__device__ __forceinline__ float fma2i(unsigned u, float z0, float z1, float acc) {
    int lo = (int)(short)(u & 0xffffu);
    int hi = ((int)u) >> 16;
    acc += (float)lo * z0 + (float)hi * z1;
    return acc;
}
__device__ __forceinline__ float fma8i(uint4 u, float4 zl, float4 zh, float acc) {
    acc = fma2i(u.x, zl.x, zl.y, acc);
    acc = fma2i(u.y, zl.z, zl.w, acc);
    acc = fma2i(u.z, zh.x, zh.y, acc);
    acc = fma2i(u.w, zh.z, zh.w, acc);
    return acc;
}
__device__ __forceinline__ int q15(float w, float inv) {
    float q = rintf(w * inv);
    q = fmaxf(-32767.0f, fminf(32767.0f, q));
    return (int)q;
}
__device__ __forceinline__ unsigned pack16(int a, int b) {
    return ((unsigned)a & 0xffffu) | ((unsigned)b << 16);
}

// one wave (64 threads) per row; rows: [0,2112) W2, [2112,2240) W1, [2240,2368) W0
__global__ __launch_bounds__(64)
void prep_kernel(const float* __restrict__ vW0, const float* __restrict__ vW1,
                 const float* __restrict__ vW2, unsigned* __restrict__ ws)
{
    const int row  = blockIdx.x;
    const int lane = threadIdx.x;
    float* scf = (float*)ws;

    if (row < kO) {                                   // vW2 row, 128 cols
        const float* src = vW2 + (size_t)row * kW;
        float m = fmaxf(fabsf(src[lane]), fabsf(src[lane + 64]));
        #pragma unroll
        for (int s = 1; s < 64; s <<= 1) m = fmaxf(m, __shfl_xor(m, s));
        float inv = (m > 0.0f) ? 32767.0f / m : 0.0f;
        if (lane == 0) scf[WS_SC2 + row] = (m > 0.0f) ? m / 32767.0f : 0.0f;
        int w = lane;
        unsigned pk = pack16(q15(src[2 * w], inv), q15(src[2 * w + 1], inv));
        int R = row >> 6, r = row & 63, q = w >> 2, e = w & 3;
        ws[WS_W2 + (((R * 16 + q) * 64 + r) << 2) + e] = pk;
    } else if (row < kO + kW) {                       // vW1 row, 128 cols
        int r = row - kO;
        const float* src = vW1 + (size_t)r * kW;
        float m = fmaxf(fabsf(src[lane]), fabsf(src[lane + 64]));
        #pragma unroll
        for (int s = 1; s < 64; s <<= 1) m = fmaxf(m, __shfl_xor(m, s));
        float inv = (m > 0.0f) ? 32767.0f / m : 0.0f;
        if (lane == 0) scf[WS_SC1 + r] = (m > 0.0f) ? m / 32767.0f : 0.0f;
        int w = lane;
        ws[WS_W1 + r * 64 + w] = pack16(q15(src[2 * w], inv), q15(src[2 * w + 1], inv));
    } else {                                          // vW0 row, 65 cols
        int r = row - kO - kW;
        const float* src = vW0 + (size_t)r * kIN;
        float m = fabsf(src[lane]);
        if (lane == 0) m = fmaxf(m, fabsf(src[64]));
        #pragma unroll
        for (int s = 1; s < 64; s <<= 1) m = fmaxf(m, __shfl_xor(m, s));
        float inv = (m > 0.0f) ? 32767.0f / m : 0.0f;
        if (lane == 0) scf[WS_SC0 + r] = (m > 0.0f) ? m / 32767.0f : 0.0f;
        if (lane < 33) {
            int c0 = 2 * lane, c1 = 2 * lane + 1;
            int qa = q15(src[c0], inv);
            int qb = (c1 < kIN) ? q15(src[c1], inv) : 0;
            ws[WS_W0 + r * 33 + lane] = pack16(qa, qb);
        }
    }
}

// amdgpu_waves_per_eu(4,4): exact-range form. 16-wave block + 141 KB LDS means
// exactly 1 block/CU = 4 waves/EU; pinning the allocator target gives the
// 128-VGPR budget. __launch_bounds__(1024,4) was NOT honored (rounds 2/3:
// VGPR stuck at 64, 78 GB of spill traffic).
// PIPE=1: depth-1 double-buffered S3 weight stream (~90 VGPRs).
// PIPE=0: loads-at-use S3 (round-0-proven ~60 VGPRs, cannot spill) — selected
// at launch time via hipFuncGetAttributes if PIPE=1 reports scratch usage.
template <int QI, int PIPE>
__global__ __attribute__((amdgpu_flat_work_group_size(1024, 1024), amdgpu_waves_per_eu(4, 4)))
void cde_kernel(
    const float* __restrict__ ts,  const float* __restrict__ ys,
    const float* __restrict__ iW0, const float* __restrict__ ib0,
    const float* __restrict__ iW1, const float* __restrict__ ib1,
    const float* __restrict__ iW2, const float* __restrict__ ib2,
    const float* __restrict__ vW0, const float* __restrict__ vb0,
    const float* __restrict__ vW1, const float* __restrict__ vb1,
    const float* __restrict__ vW2, const float* __restrict__ vb2,
    const float* __restrict__ rW,  const float* __restrict__ rb,
    const unsigned* __restrict__ wsb,
    float* __restrict__ out)
{
    const int b  = blockIdx.x;
    const int t  = threadIdx.x;
    const int r8 = t >> 3;     // 0..127
    const int g  = t & 7;      // 0..7
    const int wv = t >> 6;     // wave 0..15
    const int ln = t & 63;     // lane

    // parked weights (int16) + state. pads: s_w1 stride 68 words, s_wt stride 65
    // uint4s -> bank group depends on row index (kills the 8-way conflicts).
    __shared__ __align__(16) uint4    s_w2[4 * 1024];   // 65536 B: W2 R-blocks 0..3
    __shared__ __align__(16) uint4    s_wt[16 * 65];    // 16640 B: tail R-block 32, padded
    __shared__ __align__(16) unsigned s_w1[kW * 68];    // 34816 B: W1, padded stride
    __shared__ __align__(16) unsigned s_w0[kW * 33];    // 16896 B
    __shared__ __align__(16) float s_v[kO];             // 8448 B
    __shared__ __align__(16) float s_z1[kW], s_z2[kW];
    __shared__ __align__(16) float s_inp[kIN + 1];      // [65] = 0 pad
    __shared__ float s_y[kH], s_yhat[kH], s_e[kH];
    __shared__ float s_x[3][34];                        // x_{i-1}, x_i, x_{i+1}

    const float*    ysb   = ys + (size_t)b * kT * kD;
    const uint4*    wsW2q = (const uint4*)(wsb + WS_W2);
    const float*    scf   = (const float*)wsb;

    const float bA  = vb2[t];
    const float bB  = vb2[t + 1024];
    const float bTl = (t < 512) ? vb2[2048 + r8] : 0.0f;
    const float b0r = vb0[r8];
    const float b1r = vb1[r8];
    const float sA  = QI ? scf[WS_SC2 + t] : 0.0f;
    const float sB  = QI ? scf[WS_SC2 + t + 1024] : 0.0f;
    const float sTl = (QI && t < 512) ? scf[WS_SC2 + 2048 + r8] : 0.0f;
    const float s0r = QI ? scf[WS_SC0 + r8] : 0.0f;
    const float s1r = QI ? scf[WS_SC1 + r8] : 0.0f;

    // ---- park weights in LDS (one-time) ----
    if (QI) {
        for (int idx = t; idx < 4 * 1024; idx += BLOCK)
            s_w2[idx] = wsW2q[idx];                              // R 0..3 contiguous
        for (int idx = t; idx < 16 * 64; idx += BLOCK)
            s_wt[(idx >> 6) * 65 + (idx & 63)] = wsW2q[32768 + idx];  // R=32
        for (int idx = t; idx < kW * 64; idx += BLOCK)
            s_w1[(idx >> 6) * 68 + (idx & 63)] = wsb[WS_W1 + idx];
        for (int idx = t; idx < kW * 33; idx += BLOCK)
            s_w0[idx] = wsb[WS_W0 + idx];
    }

    // ---- x staging init: s_x[0]=x_0, s_x[1]=x_1, s_x[2]=0 ----
    float x_next = 0.0f;
    const float* yptr = nullptr;
    if (t < kC) {
        float x0v, x1v;
        if (t == 0) { x0v = ts[0]; x1v = ts[1]; }
        else {
            const float* p = ysb + (t - 1);
            x0v = p[0]; x1v = p[kD]; yptr = p + 2 * kD;
        }
        s_x[0][t] = x0v; s_x[1][t] = x1v; s_x[2][t] = 0.0f;
        x_next = x1v;
    }
    if (t == 0) s_inp[kIN] = 0.0f;          // pad
    __syncthreads();

    // ---- initial MLP (one-time, fp32) ----
    if (t < kW) {
        const float* wrow = iW0 + t * kC;
        float acc = ib0[t];
        #pragma unroll
        for (int c = 0; c < kC; c++) acc += wrow[c] * s_x[0][c];
        s_z1[t] = fmaxf(acc, 0.0f);
    }
    __syncthreads();
    if (t < kW) {
        const float4* wr = (const float4*)(iW1 + t * kW);
        const float4* z4 = (const float4*)s_z1;
        float acc = ib1[t];
        #pragma unroll 8
        for (int q = 0; q < kW / 4; q++) acc += dot4(wr[q], z4[q]);
        s_z2[t] = fmaxf(acc, 0.0f);
    }
    __syncthreads();
    if (t < kH) {
        const float4* wr = (const float4*)(iW2 + t * kW);
        const float4* z4 = (const float4*)s_z2;
        float acc = ib2[t];
        #pragma unroll 8
        for (int q = 0; q < kW / 4; q++) acc += dot4(wr[q], z4[q]);
        s_y[t] = acc; s_yhat[t] = acc;
        s_inp[1 + t] = acc;
    }
    if (t == 0) s_inp[0] = ts[0];
    __syncthreads();

    // ---- S3 pointers ----
    const uint4* gA = wsW2q + (size_t)(wv * 16) * 64 + ln;          // rows wv*64..
    const uint4* gB = wsW2q + (size_t)((wv + 16) * 16) * 64 + ln;   // rows 1024+wv*64..
    const uint4* lA = s_w2 + wv * 1024 + ln;                        // valid if wv<4
    const bool aL = (wv < 4);

    // ---- main scan: 4 barriers per step ----
    for (int i = 0; i < kT; i++) {
        const int i0  = i % 3;
        const int ip1 = (i + 1) % 3;
        const int im1 = (i + 2) % 3;

        // ===== S1: layer1 (65->128), split-k-8 ; x_{i+1} publish + x_{i+2} prefetch =====
        {
            float acc = 0.0f;
            if (QI) {
                const unsigned* rowp = s_w0 + r8 * 33;
                #pragma unroll
                for (int m = 0; m < 5; m++) {
                    int p = g + 8 * m;
                    if (p < 33) acc = fma2i(rowp[p], s_inp[2 * p], s_inp[2 * p + 1], acc);
                }
            } else {
                const float* rowp = vW0 + r8 * kIN;
                #pragma unroll
                for (int m = 0; m < 5; m++) {
                    int p = g + 8 * m;
                    if (p < 33) {
                        float w0 = rowp[2 * p];
                        float w1 = (2 * p + 1 < kIN) ? rowp[2 * p + 1] : 0.0f;
                        acc += w0 * s_inp[2 * p] + w1 * s_inp[2 * p + 1];
                    }
                }
            }
            acc += __shfl_xor(acc, 1);
            acc += __shfl_xor(acc, 2);
            acc += __shfl_xor(acc, 4);
            if (g == 0) s_z1[r8] = lipswish_f(b0r + (QI ? s0r * acc : acc));
        }
        if (t < kC && i + 1 < kT) {
            s_x[ip1][t] = x_next;
            if (i + 2 < kT) {
                if (t == 0) x_next = ts[i + 2];
                else { x_next = *yptr; yptr += kD; }
            }
        }
        __syncthreads();

        // ===== S2: layer2 (128->128), split-k-8 =====
        {
            float acc = 0.0f;
            #pragma unroll
            for (int m = 0; m < 2; m++) {
                int ch = g + 8 * m;
                const float4* z4 = (const float4*)(s_z1 + 8 * ch);
                float4 za = z4[0], zb = z4[1];
                if (QI) {
                    uint4 u = *(const uint4*)(s_w1 + r8 * 68 + 4 * ch);
                    acc = fma8i(u, za, zb, acc);
                } else {
                    const float* wr = vW1 + r8 * kW + 8 * ch;
                    acc += dot4(*(const float4*)wr, za) + dot4(*(const float4*)(wr + 4), zb);
                }
            }
            acc += __shfl_xor(acc, 1);
            acc += __shfl_xor(acc, 2);
            acc += __shfl_xor(acc, 4);
            if (g == 0) s_z2[r8] = lipswish_f(b1r + (QI ? s1r * acc : acc));
        }
        __syncthreads();

        // ===== S3 main: rows t and t+1024 =====
        if (QI) {
            float acc0 = 0.0f, acc1 = 0.0f;
            const float4* z4 = (const float4*)s_z2;
            if (PIPE) {
                // depth-1 double buffer: prefetch m+1 while computing m
                uint4 cb0 = gB[0], cb1 = gB[64];
                uint4 ca0, ca1;
                if (!aL) { ca0 = gA[0]; ca1 = gA[64]; }
                #pragma unroll
                for (int m = 0; m < 8; m++) {
                    uint4 nb0, nb1, na0, na1;
                    if (m < 7) {
                        nb0 = gB[(2 * m + 2) * 64]; nb1 = gB[(2 * m + 3) * 64];
                        if (!aL) { na0 = gA[(2 * m + 2) * 64]; na1 = gA[(2 * m + 3) * 64]; }
                    }
                    if (aL) { ca0 = lA[(2 * m) * 64]; ca1 = lA[(2 * m + 1) * 64]; }
                    float4 z0 = z4[4 * m], z1 = z4[4 * m + 1];
                    float4 z2v = z4[4 * m + 2], z3 = z4[4 * m + 3];
                    acc0 = fma8i(ca0, z0, z1, acc0);
                    acc0 = fma8i(ca1, z2v, z3, acc0);
                    acc1 = fma8i(cb0, z0, z1, acc1);
                    acc1 = fma8i(cb1, z2v, z3, acc1);
                    cb0 = nb0; cb1 = nb1;
                    if (!aL) { ca0 = na0; ca1 = na1; }
                }
            } else {
                // loads at use (round-0-proven register footprint)
                #pragma unroll 2
                for (int m = 0; m < 8; m++) {
                    uint4 wa0, wa1;
                    if (aL) { wa0 = lA[(2 * m) * 64]; wa1 = lA[(2 * m + 1) * 64]; }
                    else    { wa0 = gA[(2 * m) * 64]; wa1 = gA[(2 * m + 1) * 64]; }
                    uint4 wb0 = gB[(2 * m) * 64], wb1 = gB[(2 * m + 1) * 64];
                    float4 z0 = z4[4 * m], z1 = z4[4 * m + 1];
                    float4 z2v = z4[4 * m + 2], z3 = z4[4 * m + 3];
                    acc0 = fma8i(wa0, z0, z1, acc0);
                    acc0 = fma8i(wa1, z2v, z3, acc0);
                    acc1 = fma8i(wb0, z0, z1, acc1);
                    acc1 = fma8i(wb1, z2v, z3, acc1);
                }
            }
            s_v[t]        = fast_tanh(bA + sA * acc0);
            s_v[t + 1024] = fast_tanh(bB + sB * acc1);
        } else {
            float acc0 = 0.0f, acc1 = 0.0f;
            #pragma unroll 2
            for (int m = 0; m < 8; m++) {
                const float4* z4 = (const float4*)(s_z2 + 16 * m);
                float4 z0 = z4[0], z1 = z4[1], z2 = z4[2], z3 = z4[3];
                const float4* rA = (const float4*)(vW2 + (size_t)t * kW + 16 * m);
                const float4* rB = (const float4*)(vW2 + (size_t)(t + 1024) * kW + 16 * m);
                acc0 += dot4(rA[0], z0) + dot4(rA[1], z1) + dot4(rA[2], z2) + dot4(rA[3], z3);
                acc1 += dot4(rB[0], z0) + dot4(rB[1], z1) + dot4(rB[2], z2) + dot4(rB[3], z3);
            }
            s_v[t]        = fast_tanh(bA + acc0);
            s_v[t + 1024] = fast_tanh(bB + acc1);
        }
        // ===== S3 tail: rows 2048..2111, split-k-8 (padded LDS) =====
        if (t < 512) {
            int c0 = 16 * g;
            const float4* z4 = (const float4*)(s_z2 + c0);
            float4 z0 = z4[0], z1 = z4[1], z2 = z4[2], z3 = z4[3];
            float acc = 0.0f;
            if (QI) {
                uint4 u0 = s_wt[(2 * g) * 65 + r8];
                uint4 u1 = s_wt[(2 * g + 1) * 65 + r8];
                acc = fma8i(u0, z0, z1, acc);
                acc = fma8i(u1, z2, z3, acc);
            } else {
                const float4* wr = (const float4*)(vW2 + (size_t)(2048 + r8) * kW + c0);
                acc += dot4(wr[0], z0) + dot4(wr[1], z1) + dot4(wr[2], z2) + dot4(wr[3], z3);
            }
            acc += __shfl_xor(acc, 1);
            acc += __shfl_xor(acc, 2);
            acc += __shfl_xor(acc, 4);
            if (g == 0) s_v[2048 + r8] = fast_tanh(bTl + (QI ? sTl * acc : acc));
        }
        __syncthreads();

        // ===== S4 fused: y update (dx_{i-1}) + e/yhat (dx_i) =====
        if (t < kH) {
            const float* vr = s_v + t * kC;
            const float* xm = s_x[im1];
            const float* xc = s_x[i0];
            const float* xp = s_x[ip1];
            float dA = 0.0f, dB = 0.0f;
            #pragma unroll
            for (int c = 0; c < kC; c++) {
                float vv = vr[c];
                dA += vv * (xc[c] - xm[c]);
                dB += vv * (xp[c] - xc[c]);
            }
            if (i > 0) s_y[t] += 0.5f * (s_e[t] + dA);
            if (i < kT - 1) {
                s_e[t] = dB;
                float yh = 2.0f * s_y[t] - s_yhat[t] + dB;
                s_yhat[t] = yh;
                s_inp[1 + t] = yh;
            }
        }
        if (t == 0 && i < kT - 1) s_inp[0] = s_x[ip1][0];
        __syncthreads();
    }

    // ---- readout ----
    if (t == 0) {
        float acc = rb[0];
        #pragma unroll
        for (int h = 0; h < kH; h++) acc += s_y[h] * rW[h];
        out[b] = acc;
    }
}

extern "C" void kernel_launch(void* const* d_in, const int* in_sizes, int n_in,
                              void* d_out, int out_size, void* d_ws, size_t ws_size,
                              hipStream_t stream)
{
    const float* ts  = (const float*)d_in[0];
    const float* ys  = (const float*)d_in[1];
    const float* iW0 = (const float*)d_in[2];
    const float* ib0 = (const float*)d_in[3];
    const float* iW1 = (const float*)d_in[4];
    const float* ib1 = (const float*)d_in[5];
    const float* iW2 = (const float*)d_in[6];
    const float* ib2 = (const float*)d_in[7];
    const float* vW0 = (const float*)d_in[8];
    const float* vb0 = (const float*)d_in[9];
    const float* vW1 = (const float*)d_in[10];
    const float* vb1 = (const float*)d_in[11];
    const float* vW2 = (const float*)d_in[12];
    const float* vb2 = (const float*)d_in[13];
    const float* rW  = (const float*)d_in[14];
    const float* rb  = (const float*)d_in[15];
    float* out = (float*)d_out;
    unsigned* ws = (unsigned*)d_ws;

    if (ws_size >= (size_t)WS_TOT * 4) {
        // spill check: if the pipelined variant allocated scratch, fall back to
        // the loads-at-use variant (host-side query; graph-capture safe).
        static int pipe_sel = -1;
        if (pipe_sel < 0) {
            hipFuncAttributes fa;
            hipError_t e = hipFuncGetAttributes(
                &fa, reinterpret_cast<const void*>(&cde_kernel<1, 1>));
            pipe_sel = (e == hipSuccess && fa.localSizeBytes == 0) ? 1 : 0;
        }
        hipLaunchKernelGGL(prep_kernel, dim3(kO + kW + kW), dim3(64), 0, stream,
                           vW0, vW1, vW2, ws);
        if (pipe_sel == 1) {
            hipLaunchKernelGGL((cde_kernel<1, 1>), dim3(kB), dim3(BLOCK), 0, stream,
                               ts, ys, iW0, ib0, iW1, ib1, iW2, ib2,
                               vW0, vb0, vW1, vb1, vW2, vb2, rW, rb, ws, out);
        } else {
            hipLaunchKernelGGL((cde_kernel<1, 0>), dim3(kB), dim3(BLOCK), 0, stream,
                               ts, ys, iW0, ib0, iW1, ib1, iW2, ib2,
                               vW0, vb0, vW1, vb1, vW2, vb2, rW, rb, ws, out);
        }
    } else {
        hipLaunchKernelGGL((cde_kernel<0, 0>), dim3(kB), dim3(BLOCK), 0, stream,
                           ts, ys, iW0, ib0, iW1, ib1, iW2, ib2,
                           vW0, vb0, vW1, vb1, vW2, vb2, rW, rb, ws, out);
    }
}